// Round 4
// baseline (7184.402 us; speedup 1.0000x reference)
//
#include <hip/hip_runtime.h>
#include <hip/hip_bf16.h>
#include <math.h>

#define BATCH 4
#define SEQ   2048
#define DIM   1024
#define MROWS (SEQ*BATCH)          // 8192
#define BIGN  ((size_t)MROWS*DIM)  // 8388608 floats per buffer

typedef float v2f __attribute__((ext_vector_type(2)));

// ---------------- chunked scan for r_t = dec*r + k*v,  ret = q*r --------------
__global__ __launch_bounds__(256) void scan_a(const float* __restrict__ K,
    const float* __restrict__ V, const float* __restrict__ dec_p,
    float* __restrict__ E)
{
  int id  = blockIdx.x*256 + threadIdx.x;   // 0..262143
  int c   = id >> 12;
  int rem = id & 4095;
  int b   = rem >> 10;
  int dc  = rem & 1023;
  float dec = dec_p[dc >> 6];
  size_t base = ((size_t)b*SEQ + (size_t)c*32)*DIM + dc;
  float r = 0.f;
  #pragma unroll 4
  for (int i = 0; i < 32; ++i) {
    float kv = K[base + (size_t)i*DIM] * V[base + (size_t)i*DIM];
    r = fmaf(dec, r, kv);
  }
  E[(size_t)c*4096 + rem] = r;
}

__global__ __launch_bounds__(256) void scan_b(const float* __restrict__ E,
    const float* __restrict__ dec_p, float* __restrict__ carry)
{
  int id = blockIdx.x*256 + threadIdx.x;    // 0..4095
  int dc = id & 1023;
  float dec = dec_p[dc >> 6];
  float d2 = dec*dec, d4 = d2*d2, d8 = d4*d4, d16 = d8*d8, d32 = d16*d16;
  float r = 0.f;
  #pragma unroll 1
  for (int c = 0; c < 64; ++c) {
    carry[(size_t)c*4096 + id] = r;
    r = fmaf(d32, r, E[(size_t)c*4096 + id]);
  }
}

__global__ __launch_bounds__(256) void scan_c(const float* __restrict__ Q,
    const float* __restrict__ K, const float* __restrict__ V,
    const float* __restrict__ dec_p, const float* __restrict__ carry,
    float* __restrict__ ret)
{
  int id  = blockIdx.x*256 + threadIdx.x;
  int c   = id >> 12;
  int rem = id & 4095;
  int b   = rem >> 10;
  int dc  = rem & 1023;
  float dec = dec_p[dc >> 6];
  size_t base = ((size_t)b*SEQ + (size_t)c*32)*DIM + dc;
  float r = carry[(size_t)c*4096 + rem];
  #pragma unroll 1
  for (int i = 0; i < 32; ++i) {
    int t = c*32 + i;
    float kv = K[base + (size_t)i*DIM] * V[base + (size_t)i*DIM];
    r = fmaf(dec, r, kv);
    ret[((size_t)t*BATCH + b)*DIM + dc] = Q[base + (size_t)i*DIM] * r;
  }
}

// ---------------- fp32 tiled GEMM: C[m,n] = sum_k X[m,k]*W[n,k] (+bias) -------
// MODE 0: C = XW^T + bias
// MODE 1: g = sigmoid(XW^T + bias) -> C;  u_out = (1-g)*inp
// MODE 2: C += XW^T
// MODE 3: outf[b,t,n] = XW^T + bias   (m = t*4+b scatter), float32 output
// MODE 4: C = XW^T
// 128x128 tile, 8x8 per thread, packed v_pk_fma_f32 (r3: improved vs 64x64).
#define GM 128
#define GN 128
#define GK 16
#define LDG 132

template<int MODE>
__global__ __launch_bounds__(256) void gemm_k(
    const float* __restrict__ X, const float* __restrict__ W,
    const float* __restrict__ bias, float* __restrict__ C,
    const float* __restrict__ inp, float* __restrict__ u_out,
    float* __restrict__ outf)
{
  __shared__ float Xs[GK][LDG];
  __shared__ float Ws[GK][LDG];
  const int tid = threadIdx.x;
  const int m0 = blockIdx.y * GM;
  const int n0 = blockIdx.x * GN;
  const int tx = tid & 15, ty = tid >> 4;
  v2f acc[8][4] = {};
  #pragma unroll 1
  for (int kb = 0; kb < DIM; kb += GK) {
    #pragma unroll
    for (int h = 0; h < 2; ++h) {
      int idx = tid + h*256;
      int r   = idx >> 2;         // 0..127
      int kc  = (idx & 3) << 2;   // 0,4,8,12
      float4 xv = *(const float4*)(X + (size_t)(m0+r)*DIM + kb + kc);
      Xs[kc+0][r] = xv.x; Xs[kc+1][r] = xv.y;
      Xs[kc+2][r] = xv.z; Xs[kc+3][r] = xv.w;
      float4 wv2 = *(const float4*)(W + (size_t)(n0+r)*DIM + kb + kc);
      Ws[kc+0][r] = wv2.x; Ws[kc+1][r] = wv2.y;
      Ws[kc+2][r] = wv2.z; Ws[kc+3][r] = wv2.w;
    }
    __syncthreads();
    #pragma unroll
    for (int kk = 0; kk < GK; ++kk) {
      float4 a0 = *(const float4*)&Xs[kk][ty*8];
      float4 a1 = *(const float4*)&Xs[kk][ty*8 + 4];
      float4 w0 = *(const float4*)&Ws[kk][tx*4];        // cols tx*4..+3
      float4 w1 = *(const float4*)&Ws[kk][64 + tx*4];   // cols 64+tx*4..+3
      v2f wv[4] = {{w0.x,w0.y},{w0.z,w0.w},{w1.x,w1.y},{w1.z,w1.w}};
      float av[8] = {a0.x,a0.y,a0.z,a0.w,a1.x,a1.y,a1.z,a1.w};
      #pragma unroll
      for (int i = 0; i < 8; ++i) {
        v2f ab = {av[i], av[i]};
        #pragma unroll
        for (int j = 0; j < 4; ++j)
          acc[i][j] = __builtin_elementwise_fma(ab, wv[j], acc[i][j]);
      }
    }
    __syncthreads();
  }
  float bj[8];
  #pragma unroll
  for (int j = 0; j < 8; ++j) {
    int n = n0 + ((j < 4) ? (tx*4 + j) : (64 + tx*4 + (j - 4)));
    bj[j] = (MODE == 0 || MODE == 1 || MODE == 3) ? bias[n] : 0.f;
  }
  #pragma unroll
  for (int i = 0; i < 8; ++i) {
    int m = m0 + ty*8 + i;
    #pragma unroll
    for (int j = 0; j < 8; ++j) {
      int n = n0 + ((j < 4) ? (tx*4 + j) : (64 + tx*4 + (j - 4)));
      size_t off = (size_t)m*DIM + n;
      float vv = acc[i][j >> 1][j & 1] + bj[j];
      if (MODE == 2) vv += C[off];
      if (MODE == 1) {
        float gv = 1.f/(1.f + expf(-vv));
        C[off] = gv;
        u_out[off] = (1.f - gv) * inp[off];
      } else if (MODE == 3) {
        outf[((size_t)(m & 3)*SEQ + (size_t)(m >> 2))*DIM + n] = vv;
      } else {
        C[off] = vv;
      }
    }
  }
}

// ---------------- sequential recurrence: s_t = tanh((g_t*s_{t-1})@A^T + d_t) --
// r4 decomposition change (DS-traffic theory): r2's step time matched the
// DS-pipe arithmetic (512 ds_read_b128/CU/step), NOT sync. New split:
// 64 blocks/batch x 16 rows/block (grid 256 = 1 block/CU). Per thread:
// 1 row x 32 k-terms -> x-traffic 128B/thread (4x less), 16 ds_read_b64.
// A-fragment = 32 floats/thread (no AGPR pressure). Row reduced by a 5-step
// butterfly within the 32-lane half-wave.
//
// LDS x layout, XOR-swizzled at 8B granularity: logical word (s*32 + o)
// stored at phys word s*32 + ((o>>1 ^ (s&15))<<1) + (o&1). Read at logical
// chunk j2: lanes l5=0..31 hit bank-pair (j2^(l5&15))*2 -> 16 distinct
// pairs, 2-way aliasing = free (m136). Writes: 128 words/32 banks = data
// floor. All addresses loop-invariant (precomputed, hoisted).
//
// Sync: EXACTLY r2's proven skeleton (poll loop on 2-slot LSB-tagged ring,
// stage barrier = lgkmcnt-only, end barrier = bare s_barrier, NO pre-issued
// samples -- r3 showed they reintroduce the store-ack vmcnt drain).
// Ring: sf[2][B][512] packed words {f32 x2r, f32 x2r+1}, LSB tag
// tag(t)=((t+2)>>1)&1. Reuse proof: producing tag(T-1) implies having
// consumed slot (T-2)&1, and the producer at T saw all 512 tag(T-1) words
// (its threads poll all words), so overwriting slot T&1 is safe.
#define RBLK 256

__global__ __launch_bounds__(512, 2) void recur_k(
    const float* __restrict__ A, const float* __restrict__ g,
    const float* __restrict__ dpre, float* __restrict__ s,
    unsigned long long* __restrict__ sf)
{
  __shared__ __align__(16) float xs[1024 + 8];    // 4.1 KB
  const int tid = threadIdx.x;
  const int w   = tid >> 6;                 // wave 0..7
  const int ln  = tid & 63;
  const int h   = ln >> 5;                  // half-wave 0/1
  const int l5  = ln & 31;                  // k-slice index (32 floats)
  const int b   = blockIdx.x >> 6;          // batch 0..3
  const int blk = blockIdx.x & 63;          // block within batch
  const int row = blk*16 + w*2 + h;         // global row 0..1023

  const size_t slotstride = (size_t)BATCH*512;     // ull words per ring slot
  unsigned long long* sfb = sf + (size_t)b*512;    // this batch, slot 0

  // A fragment: (row, k in [l5*32, l5*32+32)) -> 16 v2f, logical order
  float4 atmp[8];
  #pragma unroll
  for (int j = 0; j < 8; ++j)
    atmp[j] = *(const float4*)(A + (size_t)row*DIM + l5*32 + 4*j);
  v2f a2[16];
  #pragma unroll
  for (int j = 0; j < 8; ++j) {
    a2[2*j]   = (v2f){atmp[j].x, atmp[j].y};
    a2[2*j+1] = (v2f){atmp[j].z, atmp[j].w};
  }

  // swizzled LDS offsets (loop-invariant)
  const int m15   = l5 & 15;
  const int wphys = (tid >> 4)*32 + (((tid & 15) ^ ((tid >> 4) & 15)) << 1);
  int roff[16];
  #pragma unroll
  for (int j2 = 0; j2 < 16; ++j2)
    roff[j2] = l5*32 + ((j2 ^ m15) << 1);

  // prologue prefetch (t=0)
  float2 gvc = *(const float2*)(g + (size_t)b*DIM + 2*tid);
  float  dvc = dpre[(size_t)b*DIM + row];

  #pragma unroll 1
  for (int t = 0; t < SEQ; ++t) {
    v2f acc = {0.f, 0.f};
    if (t > 0) {
      // poll the one flagged word this thread stages (x[2tid], x[2tid+1])
      const unsigned wl = ((unsigned)(t + 1) >> 1) & 1u;   // tag(t-1)
      unsigned long long* pw = sfb + (size_t)((t - 1) & 1)*slotstride + tid;
      union { unsigned long long u; float f[2]; } wv;
      int guard = 0;
      for (;;) {
        unsigned long long x0 = __hip_atomic_load(pw, __ATOMIC_RELAXED,
                                                  __HIP_MEMORY_SCOPE_AGENT);
        unsigned long long x1 = __hip_atomic_load(pw, __ATOMIC_RELAXED,
                                                  __HIP_MEMORY_SCOPE_AGENT);
        if ((unsigned)(x0 & 1u) == wl) { wv.u = x0; break; }
        if ((unsigned)(x1 & 1u) == wl) { wv.u = x1; break; }
        if (++guard > (1 << 22))       { wv.u = x1; break; }
      }

      // stage x = g * s[t-1][b] into swizzled slot (one float2 per thread)
      *(float2*)(xs + wphys) = make_float2(gvc.x * wv.f[0], gvc.y * wv.f[1]);
      asm volatile("s_waitcnt lgkmcnt(0)\n\ts_barrier" ::: "memory");

      // matvec: 32 MACs (16 pk-fma), swizzled conflict-free b64 reads
      #pragma unroll
      for (int j2 = 0; j2 < 16; ++j2) {
        v2f xv = *(const v2f*)(xs + roff[j2]);
        acc = __builtin_elementwise_fma(a2[j2], xv, acc);
      }
    }
    float sum = acc.x + acc.y;
    // butterfly over the 32 lanes of this half-wave (one row)
    sum += __shfl_xor(sum, 1, 64);
    sum += __shfl_xor(sum, 2, 64);
    sum += __shfl_xor(sum, 4, 64);
    sum += __shfl_xor(sum, 8, 64);
    sum += __shfl_xor(sum, 16, 64);
    // fast tanh: 1 - 2/(e^{2x}+1); exp2 saturates correctly at +-inf
    float zz  = sum + dvc;
    float e2x = __builtin_amdgcn_exp2f(zz * 2.8853900817779268f);
    float val = 1.0f - 2.0f * __builtin_amdgcn_rcpf(e2x + 1.0f);
    // pair with the other half's row (rows w*2, w*2+1)
    float pv = __shfl_xor(val, 32, 64);
    const unsigned tg = ((unsigned)(t + 2) >> 1) & 1u;
    if (ln == 0) {
      union { unsigned long long u; unsigned ui[2]; } pk;
      pk.ui[0] = (__float_as_uint(val) & ~1u) | tg;
      pk.ui[1] = (__float_as_uint(pv)  & ~1u) | tg;
      __hip_atomic_store(sfb + (size_t)(t & 1)*slotstride + (blk*8 + w), pk.u,
                         __ATOMIC_RELAXED, __HIP_MEMORY_SCOPE_AGENT);
      // plain store for the output GEMM (kernel-boundary visibility)
      *(float2*)(s + ((size_t)t*4 + b)*DIM + blk*16 + w*2)
          = make_float2(val, pv);
    }
    // prefetch next step's g/d (independent of the ring)
    if (t + 1 < SEQ) {
      gvc = *(const float2*)(g + ((size_t)(t + 1)*4 + b)*DIM + 2*tid);
      dvc = dpre[((size_t)(t + 1)*4 + b)*DIM + row];
    }
    // bare end barrier: keeps waves together, protects xs reuse (reads were
    // consumed before arrival); NO vmcnt drain of the publish store
    asm volatile("s_barrier" ::: "memory");
  }
}

// ------------------------------------------------------------------------------
extern "C" void kernel_launch(void* const* d_in, const int* in_sizes, int n_in,
                              void* d_out, int out_size, void* d_ws, size_t ws_size,
                              hipStream_t stream)
{
  (void)in_sizes; (void)n_in; (void)out_size;
  const float* q   = (const float*)d_in[0];
  const float* k   = (const float*)d_in[1];
  const float* v   = (const float*)d_in[2];
  const float* Wi  = (const float*)d_in[3];
  const float* bi  = (const float*)d_in[4];
  const float* Wg  = (const float*)d_in[5];
  const float* bg  = (const float*)d_in[6];
  const float* A   = (const float*)d_in[7];
  const float* Bm  = (const float*)d_in[8];
  const float* Wo  = (const float*)d_in[9];
  const float* bo  = (const float*)d_in[10];
  const float* dec = (const float*)d_in[11];

  const size_t sf_bytes = (size_t)2*BATCH*512*sizeof(unsigned long long); // 32KB
  size_t need = (4*BIGN + 2*(size_t)64*4096)*sizeof(float) + sf_bytes;
  if (ws_size < need) return;

  float* b0 = (float*)d_ws;          // ret -> u -> s
  float* b1 = b0 + BIGN;             // inp
  float* b2 = b1 + BIGN;             // g
  float* b3 = b2 + BIGN;             // d  (pre-activation constant)
  float* E     = b3 + BIGN;
  float* carry = E + (size_t)64*4096;
  unsigned long long* sf = (unsigned long long*)(carry + (size_t)64*4096);
  float* outp  = (float*)d_out;

  hipMemsetAsync(sf, 0, sf_bytes, stream);

  scan_a<<<1024, 256, 0, stream>>>(k, v, dec, E);
  scan_b<<<16,   256, 0, stream>>>(E, dec, carry);
  scan_c<<<1024, 256, 0, stream>>>(q, k, v, dec, carry, b0);

  dim3 gg(DIM/GN, MROWS/GM);   // (8, 64)
  gemm_k<0><<<gg, 256, 0, stream>>>(b0, Wi, bi, b1, nullptr, nullptr, nullptr); // inp
  gemm_k<1><<<gg, 256, 0, stream>>>(b1, Wg, bg, b2, b1, b0, nullptr);           // g, u
  gemm_k<4><<<gg, 256, 0, stream>>>(b0, A,  nullptr, b3, nullptr, nullptr, nullptr); // d  = u@A^T
  gemm_k<2><<<gg, 256, 0, stream>>>(b1, Bm, nullptr, b3, nullptr, nullptr, nullptr); // d += inp@Bm^T

  recur_k<<<RBLK, 512, 0, stream>>>(A, b2, b3, b0, sf);                         // s

  gemm_k<3><<<gg, 256, 0, stream>>>(b0, Wo, bo, nullptr, nullptr, nullptr, outp); // out
}

// Round 5
// 5030.187 us; speedup vs baseline: 1.4283x; 1.4283x over previous
//
#include <hip/hip_runtime.h>
#include <hip/hip_bf16.h>
#include <math.h>

#define BATCH 4
#define SEQ   2048
#define DIM   1024
#define MROWS (SEQ*BATCH)          // 8192
#define BIGN  ((size_t)MROWS*DIM)  // 8388608 floats per buffer

typedef float v2f __attribute__((ext_vector_type(2)));

// ---------------- chunked scan for r_t = dec*r + k*v,  ret = q*r --------------
__global__ __launch_bounds__(256) void scan_a(const float* __restrict__ K,
    const float* __restrict__ V, const float* __restrict__ dec_p,
    float* __restrict__ E)
{
  int id  = blockIdx.x*256 + threadIdx.x;   // 0..262143
  int c   = id >> 12;
  int rem = id & 4095;
  int b   = rem >> 10;
  int dc  = rem & 1023;
  float dec = dec_p[dc >> 6];
  size_t base = ((size_t)b*SEQ + (size_t)c*32)*DIM + dc;
  float r = 0.f;
  #pragma unroll 4
  for (int i = 0; i < 32; ++i) {
    float kv = K[base + (size_t)i*DIM] * V[base + (size_t)i*DIM];
    r = fmaf(dec, r, kv);
  }
  E[(size_t)c*4096 + rem] = r;
}

__global__ __launch_bounds__(256) void scan_b(const float* __restrict__ E,
    const float* __restrict__ dec_p, float* __restrict__ carry)
{
  int id = blockIdx.x*256 + threadIdx.x;    // 0..4095
  int dc = id & 1023;
  float dec = dec_p[dc >> 6];
  float d2 = dec*dec, d4 = d2*d2, d8 = d4*d4, d16 = d8*d8, d32 = d16*d16;
  float r = 0.f;
  #pragma unroll 1
  for (int c = 0; c < 64; ++c) {
    carry[(size_t)c*4096 + id] = r;
    r = fmaf(d32, r, E[(size_t)c*4096 + id]);
  }
}

__global__ __launch_bounds__(256) void scan_c(const float* __restrict__ Q,
    const float* __restrict__ K, const float* __restrict__ V,
    const float* __restrict__ dec_p, const float* __restrict__ carry,
    float* __restrict__ ret)
{
  int id  = blockIdx.x*256 + threadIdx.x;
  int c   = id >> 12;
  int rem = id & 4095;
  int b   = rem >> 10;
  int dc  = rem & 1023;
  float dec = dec_p[dc >> 6];
  size_t base = ((size_t)b*SEQ + (size_t)c*32)*DIM + dc;
  float r = carry[(size_t)c*4096 + rem];
  #pragma unroll 1
  for (int i = 0; i < 32; ++i) {
    int t = c*32 + i;
    float kv = K[base + (size_t)i*DIM] * V[base + (size_t)i*DIM];
    r = fmaf(dec, r, kv);
    ret[((size_t)t*BATCH + b)*DIM + dc] = Q[base + (size_t)i*DIM] * r;
  }
}

// ---------------- fp32 tiled GEMM: C[m,n] = sum_k X[m,k]*W[n,k] (+bias) -------
// MODE 0: C = XW^T + bias
// MODE 1: g = sigmoid(XW^T + bias) -> C;  u_out = (1-g)*inp
// MODE 2: C += XW^T
// MODE 3: outf[b,t,n] = XW^T + bias   (m = t*4+b scatter), float32 output
// MODE 4: C = XW^T
// 128x128 tile, 8x8 per thread, packed v_pk_fma_f32 (r3: improved vs 64x64).
#define GM 128
#define GN 128
#define GK 16
#define LDG 132

template<int MODE>
__global__ __launch_bounds__(256) void gemm_k(
    const float* __restrict__ X, const float* __restrict__ W,
    const float* __restrict__ bias, float* __restrict__ C,
    const float* __restrict__ inp, float* __restrict__ u_out,
    float* __restrict__ outf)
{
  __shared__ float Xs[GK][LDG];
  __shared__ float Ws[GK][LDG];
  const int tid = threadIdx.x;
  const int m0 = blockIdx.y * GM;
  const int n0 = blockIdx.x * GN;
  const int tx = tid & 15, ty = tid >> 4;
  v2f acc[8][4] = {};
  #pragma unroll 1
  for (int kb = 0; kb < DIM; kb += GK) {
    #pragma unroll
    for (int h = 0; h < 2; ++h) {
      int idx = tid + h*256;
      int r   = idx >> 2;         // 0..127
      int kc  = (idx & 3) << 2;   // 0,4,8,12
      float4 xv = *(const float4*)(X + (size_t)(m0+r)*DIM + kb + kc);
      Xs[kc+0][r] = xv.x; Xs[kc+1][r] = xv.y;
      Xs[kc+2][r] = xv.z; Xs[kc+3][r] = xv.w;
      float4 wv2 = *(const float4*)(W + (size_t)(n0+r)*DIM + kb + kc);
      Ws[kc+0][r] = wv2.x; Ws[kc+1][r] = wv2.y;
      Ws[kc+2][r] = wv2.z; Ws[kc+3][r] = wv2.w;
    }
    __syncthreads();
    #pragma unroll
    for (int kk = 0; kk < GK; ++kk) {
      float4 a0 = *(const float4*)&Xs[kk][ty*8];
      float4 a1 = *(const float4*)&Xs[kk][ty*8 + 4];
      float4 w0 = *(const float4*)&Ws[kk][tx*4];        // cols tx*4..+3
      float4 w1 = *(const float4*)&Ws[kk][64 + tx*4];   // cols 64+tx*4..+3
      v2f wv[4] = {{w0.x,w0.y},{w0.z,w0.w},{w1.x,w1.y},{w1.z,w1.w}};
      float av[8] = {a0.x,a0.y,a0.z,a0.w,a1.x,a1.y,a1.z,a1.w};
      #pragma unroll
      for (int i = 0; i < 8; ++i) {
        v2f ab = {av[i], av[i]};
        #pragma unroll
        for (int j = 0; j < 4; ++j)
          acc[i][j] = __builtin_elementwise_fma(ab, wv[j], acc[i][j]);
      }
    }
    __syncthreads();
  }
  float bj[8];
  #pragma unroll
  for (int j = 0; j < 8; ++j) {
    int n = n0 + ((j < 4) ? (tx*4 + j) : (64 + tx*4 + (j - 4)));
    bj[j] = (MODE == 0 || MODE == 1 || MODE == 3) ? bias[n] : 0.f;
  }
  #pragma unroll
  for (int i = 0; i < 8; ++i) {
    int m = m0 + ty*8 + i;
    #pragma unroll
    for (int j = 0; j < 8; ++j) {
      int n = n0 + ((j < 4) ? (tx*4 + j) : (64 + tx*4 + (j - 4)));
      size_t off = (size_t)m*DIM + n;
      float vv = acc[i][j >> 1][j & 1] + bj[j];
      if (MODE == 2) vv += C[off];
      if (MODE == 1) {
        float gv = 1.f/(1.f + expf(-vv));
        C[off] = gv;
        u_out[off] = (1.f - gv) * inp[off];
      } else if (MODE == 3) {
        outf[((size_t)(m & 3)*SEQ + (size_t)(m >> 2))*DIM + n] = vv;
      } else {
        C[off] = vv;
      }
    }
  }
}

// ---------------- sequential recurrence: s_t = tanh((g_t*s_{t-1})@A^T + d_t) --
// r5: back to r2's PROVEN sync topology (16 blocks/batch, grid 64, 2-slot
// LSB-tagged ring, lgkmcnt-only stage barrier, bare end barrier, no
// pre-issued samples), with the matvec re-decomposed to amortize x over
// rows IN REGISTERS (r2's weakness: each thread re-read 512B of x from LDS
// for a single row -> 256KB LDS reads/block/step ~= 2048 cyc, half the step;
// r4's fix broke bank-freedom and sync topology and regressed).
//
// New split: wave w owns rows r0..r0+7; lane l owns k-terms
// {256q + 4l + j, q=0..3, j=0..3} (16 per row). A-frag = 8 rows x 16 k =
// 128 floats in regs. x read ONCE per thread (4x ds_read_b128, conflict-
// free: each quarter-wave covers every bank exactly twice) and reused for
// all 8 rows -> 32KB LDS reads/block/step. 64 pk-fma per thread per step.
// Row totals: 3-step fold butterfly (masks 4,2,1 -> lane l holds row l&7)
// + 3 plain butterflies (8,16,32).
//
// Ring: sf[2][B][512] packed {f32 x2r, f32 x2r+1} with step tag in each
// float's mantissa LSB (tag(t)=((t+2)>>1)&1; LSB error 2^-24, scheme
// correctness-proven r3/r4). Thread tid polls exactly word tid (ONE load).
// Reuse proof unchanged: producing tag(T-1) implies the producer consumed
// slot (T-2)&1, so overwrite of slot T&1 at T is safe.
#define RBLK 64

__global__ __launch_bounds__(512, 2) void recur_k(
    const float* __restrict__ A, const float* __restrict__ g,
    const float* __restrict__ dpre, float* __restrict__ s,
    unsigned long long* __restrict__ sf)
{
  __shared__ __align__(16) float xs[2][1024];   // 8 KB, double-buffered
  const int tid = threadIdx.x;
  const int w   = tid >> 6;                 // wave 0..7
  const int ln  = tid & 63;
  const int b   = blockIdx.x >> 4;          // batch 0..3
  const int blk = blockIdx.x & 15;          // block within batch
  const int r0  = blk*64 + w*8;             // first row of this wave
  const int myrow = r0 + (ln & 7);          // row this lane will hold

  const size_t slotstride = (size_t)BATCH*512;     // ull words per ring slot
  unsigned long long* sfb = sf + (size_t)b*512;    // this batch, slot 0

  // A fragment: 8 rows x {256q + 4*ln .. +3}
  v2f a2[8][4][2];
  #pragma unroll
  for (int r = 0; r < 8; ++r)
    #pragma unroll
    for (int q = 0; q < 4; ++q) {
      float4 t4 = *(const float4*)(A + (size_t)(r0 + r)*DIM + q*256 + ln*4);
      a2[r][q][0] = (v2f){t4.x, t4.y};
      a2[r][q][1] = (v2f){t4.z, t4.w};
    }

  // prologue prefetch (t=0)
  float2 gvc = *(const float2*)(g + (size_t)b*DIM + 2*tid);
  float  dvc = dpre[(size_t)b*DIM + myrow];

  #pragma unroll 1
  for (int t = 0; t < SEQ; ++t) {
    float sr[8] = {};
    if (t > 0) {
      // poll the one flagged word this thread stages (x[2tid], x[2tid+1])
      const unsigned wl = ((unsigned)(t + 1) >> 1) & 1u;   // tag(t-1)
      unsigned long long* pw = sfb + (size_t)((t - 1) & 1)*slotstride + tid;
      union { unsigned long long u; float f[2]; } wv;
      int guard = 0;
      for (;;) {
        unsigned long long x0 = __hip_atomic_load(pw, __ATOMIC_RELAXED,
                                                  __HIP_MEMORY_SCOPE_AGENT);
        unsigned long long x1 = __hip_atomic_load(pw, __ATOMIC_RELAXED,
                                                  __HIP_MEMORY_SCOPE_AGENT);
        if ((unsigned)(x0 & 1u) == wl) { wv.u = x0; break; }
        if ((unsigned)(x1 & 1u) == wl) { wv.u = x1; break; }
        if (++guard > (1 << 22))       { wv.u = x1; break; }
      }

      // stage x = g * s[t-1][b] (linear layout, conflict-free float2 write)
      float* xb = xs[t & 1];
      *(float2*)(xb + 2*tid) = make_float2(gvc.x * wv.f[0], gvc.y * wv.f[1]);
      asm volatile("s_waitcnt lgkmcnt(0)\n\ts_barrier" ::: "memory");

      // x slice ONCE into regs (4x b128, conflict-free), reuse for 8 rows
      v2f xq[4][2];
      #pragma unroll
      for (int q = 0; q < 4; ++q) {
        float4 xt = *(const float4*)(xb + q*256 + ln*4);
        xq[q][0] = (v2f){xt.x, xt.y};
        xq[q][1] = (v2f){xt.z, xt.w};
      }
      #pragma unroll
      for (int r = 0; r < 8; ++r) {
        v2f acc = {0.f, 0.f};
        #pragma unroll
        for (int q = 0; q < 4; ++q) {
          acc = __builtin_elementwise_fma(a2[r][q][0], xq[q][0], acc);
          acc = __builtin_elementwise_fma(a2[r][q][1], xq[q][1], acc);
        }
        sr[r] = acc.x + acc.y;
      }
    }
    // fold reduce: masks 4,2,1 (lane l ends with row l&7), then 8,16,32
    float v4[4];
    #pragma unroll
    for (int i = 0; i < 4; ++i) {
      float lo = sr[i]   + __shfl_xor(sr[i],   4, 64);
      float hi = sr[i+4] + __shfl_xor(sr[i+4], 4, 64);
      v4[i] = (ln & 4) ? hi : lo;
    }
    float v2_[2];
    #pragma unroll
    for (int i = 0; i < 2; ++i) {
      float lo = v4[i]   + __shfl_xor(v4[i],   2, 64);
      float hi = v4[i+2] + __shfl_xor(v4[i+2], 2, 64);
      v2_[i] = (ln & 2) ? hi : lo;
    }
    float v1;
    {
      float lo = v2_[0] + __shfl_xor(v2_[0], 1, 64);
      float hi = v2_[1] + __shfl_xor(v2_[1], 1, 64);
      v1 = (ln & 1) ? hi : lo;
    }
    v1 += __shfl_xor(v1, 8, 64);
    v1 += __shfl_xor(v1, 16, 64);
    v1 += __shfl_xor(v1, 32, 64);
    // fast tanh: 1 - 2/(e^{2x}+1); exp2 saturates correctly at +-inf
    float zz  = v1 + dvc;
    float e2x = __builtin_amdgcn_exp2f(zz * 2.8853900817779268f);
    float val = 1.0f - 2.0f * __builtin_amdgcn_rcpf(e2x + 1.0f);
    float pv  = __shfl_xor(val, 1, 64);   // lane 2j gets row 2j+1's value
    const unsigned tg = ((unsigned)(t + 2) >> 1) & 1u;
    if (ln < 8 && !(ln & 1)) {
      union { unsigned long long u; unsigned ui[2]; } pk;
      pk.ui[0] = (__float_as_uint(val) & ~1u) | tg;
      pk.ui[1] = (__float_as_uint(pv)  & ~1u) | tg;
      __hip_atomic_store(
          sfb + (size_t)(t & 1)*slotstride + (blk*32 + w*4 + (ln >> 1)),
          pk.u, __ATOMIC_RELAXED, __HIP_MEMORY_SCOPE_AGENT);
      // plain store for the output GEMM (kernel-boundary visibility)
      *(float2*)(s + ((size_t)t*4 + b)*DIM + r0 + ln) = make_float2(val, pv);
    }
    // prefetch next step's g/d (independent of the ring)
    if (t + 1 < SEQ) {
      gvc = *(const float2*)(g + ((size_t)(t + 1)*4 + b)*DIM + 2*tid);
      dvc = dpre[((size_t)(t + 1)*4 + b)*DIM + myrow];
    }
    // bare end barrier: keeps waves together; xs is double-buffered; NO
    // vmcnt drain of the publish store (r3's lesson)
    asm volatile("s_barrier" ::: "memory");
  }
}

// ------------------------------------------------------------------------------
extern "C" void kernel_launch(void* const* d_in, const int* in_sizes, int n_in,
                              void* d_out, int out_size, void* d_ws, size_t ws_size,
                              hipStream_t stream)
{
  (void)in_sizes; (void)n_in; (void)out_size;
  const float* q   = (const float*)d_in[0];
  const float* k   = (const float*)d_in[1];
  const float* v   = (const float*)d_in[2];
  const float* Wi  = (const float*)d_in[3];
  const float* bi  = (const float*)d_in[4];
  const float* Wg  = (const float*)d_in[5];
  const float* bg  = (const float*)d_in[6];
  const float* A   = (const float*)d_in[7];
  const float* Bm  = (const float*)d_in[8];
  const float* Wo  = (const float*)d_in[9];
  const float* bo  = (const float*)d_in[10];
  const float* dec = (const float*)d_in[11];

  const size_t sf_bytes = (size_t)2*BATCH*512*sizeof(unsigned long long); // 32KB
  size_t need = (4*BIGN + 2*(size_t)64*4096)*sizeof(float) + sf_bytes;
  if (ws_size < need) return;

  float* b0 = (float*)d_ws;          // ret -> u -> s
  float* b1 = b0 + BIGN;             // inp
  float* b2 = b1 + BIGN;             // g
  float* b3 = b2 + BIGN;             // d  (pre-activation constant)
  float* E     = b3 + BIGN;
  float* carry = E + (size_t)64*4096;
  unsigned long long* sf = (unsigned long long*)(carry + (size_t)64*4096);
  float* outp  = (float*)d_out;

  hipMemsetAsync(sf, 0, sf_bytes, stream);

  scan_a<<<1024, 256, 0, stream>>>(k, v, dec, E);
  scan_b<<<16,   256, 0, stream>>>(E, dec, carry);
  scan_c<<<1024, 256, 0, stream>>>(q, k, v, dec, carry, b0);

  dim3 gg(DIM/GN, MROWS/GM);   // (8, 64)
  gemm_k<0><<<gg, 256, 0, stream>>>(b0, Wi, bi, b1, nullptr, nullptr, nullptr); // inp
  gemm_k<1><<<gg, 256, 0, stream>>>(b1, Wg, bg, b2, b1, b0, nullptr);           // g, u
  gemm_k<4><<<gg, 256, 0, stream>>>(b0, A,  nullptr, b3, nullptr, nullptr, nullptr); // d  = u@A^T
  gemm_k<2><<<gg, 256, 0, stream>>>(b1, Bm, nullptr, b3, nullptr, nullptr, nullptr); // d += inp@Bm^T

  recur_k<<<RBLK, 512, 0, stream>>>(A, b2, b3, b0, sf);                         // s

  gemm_k<3><<<gg, 256, 0, stream>>>(b0, Wo, bo, nullptr, nullptr, nullptr, outp); // out
}